// Round 8
// baseline (476.831 us; speedup 1.0000x reference)
//
#include <hip/hip_runtime.h>
#include <math.h>

#define D 128
#define NCLS 40

typedef unsigned int u32;
typedef __attribute__((ext_vector_type(8))) short short8;
typedef __attribute__((ext_vector_type(4))) float f32x4;
typedef __attribute__((ext_vector_type(4))) int v4i;

__device__ inline float bflo(u32 u){ return __uint_as_float(u << 16); }
__device__ inline float bfhi(u32 u){ return __uint_as_float(u & 0xffff0000u); }
__device__ inline u32 pack2bf(float a, float b){
  u32 ua = __float_as_uint(a), ub = __float_as_uint(b);
  ua += 0x7fffu + ((ua >> 16) & 1u);
  ub += 0x7fffu + ((ub >> 16) & 1u);
  return (ua >> 16) | (ub & 0xffff0000u);
}
__device__ inline unsigned short pack1bf(float a){
  u32 ua = __float_as_uint(a);
  ua += 0x7fffu + ((ua >> 16) & 1u);
  return (unsigned short)(ua >> 16);
}

// ---------------- fused prep: zero deg + x->bf16 + all weight converts ----------------
// block ranges: [0,nbX) f2bf | 64 Wt1 | 64 Wt2 | 32 Wt3b+bias3b | rest zero deg
__global__ __launch_bounds__(256) void prep_k(
    const float4* __restrict__ x4, uint2* __restrict__ xb, int n4,
    const float* __restrict__ W1l, const float* __restrict__ W1r, u32* __restrict__ Wt1,
    const float* __restrict__ W2l, const float* __restrict__ W2r, u32* __restrict__ Wt2,
    const float* __restrict__ W3l, const float* __restrict__ W3r,
    u32* __restrict__ Wt3b, float* __restrict__ bias3b, const float* __restrict__ b3,
    int* __restrict__ deg, int N, int nbX)
{
  const int b = blockIdx.x;
  const int tid = threadIdx.x;
  if (b < nbX){
    int i = b * 256 + tid;
    if (i < n4){
      float4 v = x4[i];
      xb[i] = make_uint2(pack2bf(v.x, v.y), pack2bf(v.z, v.w));
    }
  } else if (b < nbX + 128){
    const bool first = (b < nbX + 64);
    const float* Wl = first ? W1l : W2l;
    const float* Wr = first ? W1r : W2r;
    u32* Wt = first ? Wt1 : Wt2;
    int i = ((b - nbX) & 63) * 256 + tid;         // 0..16383
    int nn = i >> 7, kp = i & 127;
    int k = kp * 2;
    float a, c;
    if (k < 128){ a = Wl[(size_t)k * 128 + nn]; c = Wl[(size_t)(k + 1) * 128 + nn]; }
    else        { a = Wr[(size_t)(k - 128) * 128 + nn]; c = Wr[(size_t)(k - 127) * 128 + nn]; }
    Wt[(size_t)nn * 128 + kp] = pack2bf(a, c);
  } else if (b < nbX + 160){
    // Wt3b[128 out][64 u32 k], K=128: out 0..39 = W3l^T, 64..103 = W3r^T, else 0
    int i = (b - nbX - 128) * 256 + tid;          // 0..8191
    if (i < 128 * 64){
      int nn = i >> 6, kp = i & 63;
      int k = kp * 2;
      float a = 0.f, c = 0.f;
      if (nn < NCLS){
        a = W3l[(size_t)k * NCLS + nn]; c = W3l[(size_t)(k + 1) * NCLS + nn];
      } else if (nn >= 64 && nn < 64 + NCLS){
        int cc = nn - 64;
        a = W3r[(size_t)k * NCLS + cc]; c = W3r[(size_t)(k + 1) * NCLS + cc];
      }
      Wt3b[(size_t)nn * 64 + kp] = pack2bf(a, c);
    }
    if (b == nbX + 128 && tid < 128)
      bias3b[tid] = (tid >= 64 && tid < 64 + NCLS) ? b3[tid - 64] : 0.f;
  } else {
    int i = (b - nbX - 160) * 256 + tid;
    if (i < N) deg[i] = 0;
  }
}

// ---------------- CSR build ----------------

// nt loads: edge stream must not evict deg/pos/csr lines from L2
__global__ void count_deg_k(const int* __restrict__ dst, int* __restrict__ deg, int E4){
  int e = blockIdx.x * blockDim.x + threadIdx.x;
  if (e < E4){
    v4i d = __builtin_nontemporal_load((const v4i*)(dst) + e);
    atomicAdd(&deg[d.x], 1); atomicAdd(&deg[d.y], 1);
    atomicAdd(&deg[d.z], 1); atomicAdd(&deg[d.w], 1);
  }
}

__global__ void scan_excl_k(const int* __restrict__ in, int* __restrict__ out,
                            int* __restrict__ bsum, int n){
  __shared__ int sm[1024];
  int tid = threadIdx.x;
  int i = blockIdx.x * blockDim.x + tid;
  int v = (i < n) ? in[i] : 0;
  sm[tid] = v; __syncthreads();
  int acc = v;
  for (int off = 1; off < (int)blockDim.x; off <<= 1){
    int t = (tid >= off) ? sm[tid - off] : 0;
    __syncthreads();
    acc += t; sm[tid] = acc;
    __syncthreads();
  }
  if (i < n) out[i] = acc - v;
  if (bsum && tid == (int)blockDim.x - 1) bsum[blockIdx.x] = acc;
}

__global__ void finalize_k(int* __restrict__ csr_off, const int* __restrict__ bsum_s,
                           const int* __restrict__ deg, float* __restrict__ deg_inv,
                           int* __restrict__ pos, int n, int E){
  int i = blockIdx.x * blockDim.x + threadIdx.x;
  if (i < n){
    csr_off[i] += bsum_s[i >> 10];
    deg_inv[i] = 1.0f / fmaxf((float)deg[i], 1.0f);
    pos[i] = 0;
  }
  if (i == 0) csr_off[n] = E;
}

// dst-range-filtered CSR fill (team r = blockIdx&7 -> nodes [r*span,(r+1)*span))
// nt edge reads: don't evict the team's dirty csr_src lines from its XCD L2
__global__ __launch_bounds__(256) void fill_filter_k(
    const int* __restrict__ src, const int* __restrict__ dst,
    const int* __restrict__ coff, int* __restrict__ pos,
    int* __restrict__ csr_src, int E4, int span)
{
  const int r = blockIdx.x & 7;
  const int c = blockIdx.x >> 3;
  const int lo = r * span, hi = lo + span;
  const int nthr = (gridDim.x >> 3) * 256;
  for (int i = c * 256 + threadIdx.x; i < E4; i += nthr){
    v4i d = __builtin_nontemporal_load((const v4i*)(dst) + i);
    v4i s = __builtin_nontemporal_load((const v4i*)(src) + i);
    if (d.x >= lo && d.x < hi){ int p = atomicAdd(&pos[d.x], 1); csr_src[coff[d.x] + p] = s.x; }
    if (d.y >= lo && d.y < hi){ int p = atomicAdd(&pos[d.y], 1); csr_src[coff[d.y] + p] = s.y; }
    if (d.z >= lo && d.z < hi){ int p = atomicAdd(&pos[d.z], 1); csr_src[coff[d.z] + p] = s.z; }
    if (d.w >= lo && d.w < hi){ int p = atomicAdd(&pos[d.w], 1); csr_src[coff[d.w] + p] = s.w; }
  }
}

// ---------------- mean aggregation (bf16 gather via CSR), 4-way unrolled ----------------
__device__ inline void add8(float* acc, uint4 v){
  acc[0] += bflo(v.x); acc[1] += bfhi(v.x);
  acc[2] += bflo(v.y); acc[3] += bfhi(v.y);
  acc[4] += bflo(v.z); acc[5] += bfhi(v.z);
  acc[6] += bflo(v.w); acc[7] += bfhi(v.w);
}

__global__ __launch_bounds__(256) void aggregate_k(
    const u32* __restrict__ feat, const int* __restrict__ coff,
    const int* __restrict__ csr_src, const float* __restrict__ deg_inv,
    u32* __restrict__ agg, int n)
{
  const int g = threadIdx.x >> 4;
  const int lane = threadIdx.x & 15;
  const int node = blockIdx.x * 16 + g;
  if (node >= n) return;
  const int lo = coff[node], hi = coff[node + 1];
  const uint4* __restrict__ f4 = (const uint4*)feat;
  float acc[8] = {0.f,0.f,0.f,0.f,0.f,0.f,0.f,0.f};
  int e = lo;
  for (; e + 3 < hi; e += 4){
    int s0 = csr_src[e], s1 = csr_src[e + 1];
    int s2 = csr_src[e + 2], s3 = csr_src[e + 3];
    uint4 v0 = f4[(size_t)s0 * 16 + lane];
    uint4 v1 = f4[(size_t)s1 * 16 + lane];
    uint4 v2 = f4[(size_t)s2 * 16 + lane];
    uint4 v3 = f4[(size_t)s3 * 16 + lane];
    add8(acc, v0); add8(acc, v1); add8(acc, v2); add8(acc, v3);
  }
  for (; e < hi; ++e){
    uint4 v0 = f4[(size_t)csr_src[e] * 16 + lane];
    add8(acc, v0);
  }
  const float di = deg_inv[node];
  uint4 o;
  o.x = pack2bf(acc[0] * di, acc[1] * di);
  o.y = pack2bf(acc[2] * di, acc[3] * di);
  o.z = pack2bf(acc[4] * di, acc[5] * di);
  o.w = pack2bf(acc[6] * di, acc[7] * di);
  ((uint4*)agg)[(size_t)node * 16 + lane] = o;
}

// ---------------- MFMA dense: out = relu([A1|A2] @ Wt^T + bias), bf16, K=256 ----------------
__global__ __launch_bounds__(256) void gemm_mfma_k(
    const u32* __restrict__ A1, const u32* __restrict__ A2,
    const u32* __restrict__ Wt, const float* __restrict__ bias,
    u32* __restrict__ out, int n)
{
  __shared__ u32 As_u[128 * 20];   // row stride 20 u32 = 40 bf16
  __shared__ u32 Bs_u[128 * 20];
  const int tid = threadIdx.x;
  const int row0 = blockIdx.x * 128;
  const int l = tid & 63, w = tid >> 6;
  const int lm = l & 15, lq = l >> 4;

  f32x4 acc[2][8];
  #pragma unroll
  for (int mi = 0; mi < 2; mi++)
    #pragma unroll
    for (int ni = 0; ni < 8; ni++) acc[mi][ni] = (f32x4){0.f, 0.f, 0.f, 0.f};

  for (int kt = 0; kt < 8; ++kt){
    const u32* Ap = (kt < 4) ? A1 : A2;
    const int ko = (kt & 3) * 16;
    #pragma unroll
    for (int i = 0; i < 2; i++){
      int chunk = tid + 256 * i;
      int row = chunk >> 2, q = chunk & 3;
      uint4 av = make_uint4(0, 0, 0, 0);
      int gr = row0 + row;
      if (gr < n) av = *(const uint4*)(Ap + (size_t)gr * 64 + ko + q * 4);
      *(uint4*)&As_u[row * 20 + q * 4] = av;
      uint4 bv = *(const uint4*)(Wt + (size_t)row * 128 + kt * 16 + q * 4);
      *(uint4*)&Bs_u[row * 20 + q * 4] = bv;
    }
    __syncthreads();
    short8 af0 = *(const short8*)&As_u[(w * 32 + lm) * 20 + lq * 4];
    short8 af1 = *(const short8*)&As_u[(w * 32 + 16 + lm) * 20 + lq * 4];
    #pragma unroll
    for (int ni = 0; ni < 8; ni++){
      short8 bf = *(const short8*)&Bs_u[(ni * 16 + lm) * 20 + lq * 4];
      acc[0][ni] = __builtin_amdgcn_mfma_f32_16x16x32_bf16(af0, bf, acc[0][ni], 0, 0, 0);
      acc[1][ni] = __builtin_amdgcn_mfma_f32_16x16x32_bf16(af1, bf, acc[1][ni], 0, 0, 0);
    }
    __syncthreads();
  }

  float bb[8];
  #pragma unroll
  for (int ni = 0; ni < 8; ni++) bb[ni] = bias[ni * 16 + lm];
  unsigned short* outp = (unsigned short*)out;
  #pragma unroll
  for (int mi = 0; mi < 2; mi++){
    #pragma unroll
    for (int r = 0; r < 4; r++){
      int row = row0 + w * 32 + mi * 16 + lq * 4 + r;
      if (row < n){
        #pragma unroll
        for (int ni = 0; ni < 8; ni++){
          float v = fmaxf(acc[mi][ni][r] + bb[ni], 0.f);
          outp[(size_t)row * 128 + ni * 16 + lm] = pack1bf(v);
        }
      }
    }
  }
}

// ---------------- layer-3 pre-GEMM (K=128, no relu): yz = h @ Wt3b^T + bias3b ----------------
__global__ __launch_bounds__(256) void gemm3_mfma_k(
    const u32* __restrict__ A, const u32* __restrict__ Wt3b,
    const float* __restrict__ bias, u32* __restrict__ out, int n)
{
  __shared__ u32 As_u[128 * 20];
  __shared__ u32 Bs_u[128 * 20];
  const int tid = threadIdx.x;
  const int row0 = blockIdx.x * 128;
  const int l = tid & 63, w = tid >> 6;
  const int lm = l & 15, lq = l >> 4;

  f32x4 acc[2][8];
  #pragma unroll
  for (int mi = 0; mi < 2; mi++)
    #pragma unroll
    for (int ni = 0; ni < 8; ni++) acc[mi][ni] = (f32x4){0.f, 0.f, 0.f, 0.f};

  for (int kt = 0; kt < 4; ++kt){
    #pragma unroll
    for (int i = 0; i < 2; i++){
      int chunk = tid + 256 * i;
      int row = chunk >> 2, q = chunk & 3;
      uint4 av = make_uint4(0, 0, 0, 0);
      int gr = row0 + row;
      if (gr < n) av = *(const uint4*)(A + (size_t)gr * 64 + kt * 16 + q * 4);
      *(uint4*)&As_u[row * 20 + q * 4] = av;
      uint4 bv = *(const uint4*)(Wt3b + (size_t)row * 64 + kt * 16 + q * 4);
      *(uint4*)&Bs_u[row * 20 + q * 4] = bv;
    }
    __syncthreads();
    short8 af0 = *(const short8*)&As_u[(w * 32 + lm) * 20 + lq * 4];
    short8 af1 = *(const short8*)&As_u[(w * 32 + 16 + lm) * 20 + lq * 4];
    #pragma unroll
    for (int ni = 0; ni < 8; ni++){
      short8 bf = *(const short8*)&Bs_u[(ni * 16 + lm) * 20 + lq * 4];
      acc[0][ni] = __builtin_amdgcn_mfma_f32_16x16x32_bf16(af0, bf, acc[0][ni], 0, 0, 0);
      acc[1][ni] = __builtin_amdgcn_mfma_f32_16x16x32_bf16(af1, bf, acc[1][ni], 0, 0, 0);
    }
    __syncthreads();
  }

  float bb[8];
  #pragma unroll
  for (int ni = 0; ni < 8; ni++) bb[ni] = bias[ni * 16 + lm];
  unsigned short* outp = (unsigned short*)out;
  #pragma unroll
  for (int mi = 0; mi < 2; mi++){
    #pragma unroll
    for (int r = 0; r < 4; r++){
      int row = row0 + w * 32 + mi * 16 + lq * 4 + r;
      if (row < n){
        #pragma unroll
        for (int ni = 0; ni < 8; ni++){
          float v = acc[mi][ni][r] + bb[ni];
          outp[(size_t)row * 128 + ni * 16 + lm] = pack1bf(v);
        }
      }
    }
  }
}

// ---------------- fused: out = log_softmax(mean-gather(y) + z) ----------------
__global__ __launch_bounds__(256) void agg_softmax_k(
    const u32* __restrict__ yz, const int* __restrict__ coff,
    const int* __restrict__ csr_src, const float* __restrict__ deg_inv,
    float* __restrict__ out, int n)
{
  const int g = threadIdx.x >> 3;
  const int lane = threadIdx.x & 7;
  const int node = blockIdx.x * 32 + g;
  if (node >= n) return;
  const int lo = coff[node], hi = coff[node + 1];
  const uint4* __restrict__ f4 = (const uint4*)yz;    // 16 uint4 per row; y = first 8
  float acc[8] = {0.f,0.f,0.f,0.f,0.f,0.f,0.f,0.f};
  int e = lo;
  for (; e + 3 < hi; e += 4){
    int s0 = csr_src[e], s1 = csr_src[e + 1];
    int s2 = csr_src[e + 2], s3 = csr_src[e + 3];
    uint4 v0 = f4[(size_t)s0 * 16 + lane];
    uint4 v1 = f4[(size_t)s1 * 16 + lane];
    uint4 v2 = f4[(size_t)s2 * 16 + lane];
    uint4 v3 = f4[(size_t)s3 * 16 + lane];
    add8(acc, v0); add8(acc, v1); add8(acc, v2); add8(acc, v3);
  }
  for (; e < hi; ++e){
    uint4 v0 = f4[(size_t)csr_src[e] * 16 + lane];
    add8(acc, v0);
  }
  const float di = deg_inv[node];
  uint4 zv = f4[(size_t)node * 16 + 8 + lane];
  float v[8];
  v[0] = acc[0] * di + bflo(zv.x); v[1] = acc[1] * di + bfhi(zv.x);
  v[2] = acc[2] * di + bflo(zv.y); v[3] = acc[3] * di + bfhi(zv.y);
  v[4] = acc[4] * di + bflo(zv.z); v[5] = acc[5] * di + bfhi(zv.z);
  v[6] = acc[6] * di + bflo(zv.w); v[7] = acc[7] * di + bfhi(zv.w);
  const bool valid = (lane < 5);
  float m = -INFINITY;
  if (valid){
    #pragma unroll
    for (int j = 0; j < 8; j++) m = fmaxf(m, v[j]);
  }
  #pragma unroll
  for (int off = 1; off < 8; off <<= 1) m = fmaxf(m, __shfl_xor(m, off, 64));
  float s = 0.f;
  if (valid){
    #pragma unroll
    for (int j = 0; j < 8; j++) s += __expf(v[j] - m);
  }
  #pragma unroll
  for (int off = 1; off < 8; off <<= 1) s += __shfl_xor(s, off, 64);
  const float ls = m + logf(s);
  if (valid){
    float* op = out + (size_t)node * NCLS + lane * 8;
    *(float4*)op     = make_float4(v[0]-ls, v[1]-ls, v[2]-ls, v[3]-ls);
    *(float4*)(op+4) = make_float4(v[4]-ls, v[5]-ls, v[6]-ls, v[7]-ls);
  }
}

// ---------------- launch ----------------

extern "C" void kernel_launch(void* const* d_in, const int* in_sizes, int n_in,
                              void* d_out, int out_size, void* d_ws, size_t ws_size,
                              hipStream_t stream) {
  const float* x   = (const float*)d_in[0];
  const int*   ei  = (const int*)d_in[1];
  const float* W1l = (const float*)d_in[2];
  const float* b1  = (const float*)d_in[3];
  const float* W1r = (const float*)d_in[4];
  const float* W2l = (const float*)d_in[5];
  const float* b2  = (const float*)d_in[6];
  const float* W2r = (const float*)d_in[7];
  const float* W3l = (const float*)d_in[8];
  const float* b3  = (const float*)d_in[9];
  const float* W3r = (const float*)d_in[10];

  const int N = in_sizes[0] / D;       // 100000
  const int E = in_sizes[1] / 2;       // 1600000
  const int* src = ei;
  const int* dst = ei + E;

  char* ws = (char*)d_ws;
  auto alloc = [&](size_t bytes) -> void* {
    void* p = (void*)ws;
    ws += (bytes + 255) & ~(size_t)255;
    return p;
  };
  int*   deg_i    = (int*)  alloc((size_t)N * 4);
  int*   csr_off  = (int*)  alloc((size_t)(N + 1) * 4);
  int*   pos      = (int*)  alloc((size_t)N * 4);
  int*   bsum     = (int*)  alloc(1024);
  int*   bsum_s   = (int*)  alloc(1024);
  float* deg_inv  = (float*)alloc((size_t)N * 4);
  int*   csr_src  = (int*)  alloc((size_t)E * 4);
  u32*   xb       = (u32*)  alloc((size_t)N * D * 2);
  u32*   agg      = (u32*)  alloc((size_t)N * D * 2);
  u32*   hbuf     = (u32*)  alloc((size_t)N * D * 2);
  u32*   yz       = (u32*)  alloc((size_t)N * D * 2);
  u32*   Wt1      = (u32*)  alloc((size_t)128 * 128 * 4);
  u32*   Wt2      = (u32*)  alloc((size_t)128 * 128 * 4);
  u32*   Wt3b     = (u32*)  alloc((size_t)128 * 64 * 4);
  float* bias3b   = (float*)alloc((size_t)128 * 4);

  // fused prep: x->bf16, weight converts, zero deg
  const int n4 = N * D / 4;
  const int nbX = (n4 + 255) / 256;
  const int nbZ = (N + 255) / 256;
  prep_k<<<nbX + 160 + nbZ, 256, 0, stream>>>(
      (const float4*)x, (uint2*)xb, n4,
      W1l, W1r, Wt1, W2l, W2r, Wt2,
      W3l, W3r, Wt3b, bias3b, b3,
      deg_i, N, nbX);

  // CSR build
  count_deg_k<<<(E / 4 + 255) / 256, 256, 0, stream>>>(dst, deg_i, E / 4);
  const int NB = (N + 1023) / 1024;
  scan_excl_k<<<NB, 1024, 0, stream>>>(deg_i, csr_off, bsum, N);
  scan_excl_k<<<1, 128, 0, stream>>>(bsum, bsum_s, nullptr, NB);
  finalize_k<<<(N + 255) / 256, 256, 0, stream>>>(csr_off, bsum_s, deg_i, deg_inv, pos, N, E);
  const int span = (N + 7) / 8;
  fill_filter_k<<<2048, 256, 0, stream>>>(src, dst, csr_off, pos, csr_src, E / 4, span);

  const int gblocks = (N + 127) / 128;
  const int ablocks = (N + 15) / 16;
  // layer 1
  aggregate_k<<<ablocks, 256, 0, stream>>>(xb, csr_off, csr_src, deg_inv, agg, N);
  gemm_mfma_k<<<gblocks, 256, 0, stream>>>(agg, xb, Wt1, b1, hbuf, N);
  // layer 2
  aggregate_k<<<ablocks, 256, 0, stream>>>(hbuf, csr_off, csr_src, deg_inv, agg, N);
  gemm_mfma_k<<<gblocks, 256, 0, stream>>>(agg, hbuf, Wt2, b2, hbuf, N);
  // layer 3: yz = h@[W3l|W3r]+b (K=128), then fused mean-gather + log_softmax
  gemm3_mfma_k<<<gblocks, 256, 0, stream>>>(hbuf, Wt3b, bias3b, yz, N);
  agg_softmax_k<<<(N + 31) / 32, 256, 0, stream>>>(yz, csr_off, csr_src, deg_inv,
                                                   (float*)d_out, N);
}

// Round 9
// 459.741 us; speedup vs baseline: 1.0372x; 1.0372x over previous
//
#include <hip/hip_runtime.h>
#include <math.h>

#define D 128
#define NCLS 40
#define NBLK_P1 256      // partition blocks; bucket = 128 nodes, nbuk <= 1024

typedef unsigned int u32;
typedef __attribute__((ext_vector_type(8))) short short8;
typedef __attribute__((ext_vector_type(4))) float f32x4;

__device__ inline float bflo(u32 u){ return __uint_as_float(u << 16); }
__device__ inline float bfhi(u32 u){ return __uint_as_float(u & 0xffff0000u); }
__device__ inline u32 pack2bf(float a, float b){
  u32 ua = __float_as_uint(a), ub = __float_as_uint(b);
  ua += 0x7fffu + ((ua >> 16) & 1u);
  ub += 0x7fffu + ((ub >> 16) & 1u);
  return (ua >> 16) | (ub & 0xffff0000u);
}
__device__ inline unsigned short pack1bf(float a){
  u32 ua = __float_as_uint(a);
  ua += 0x7fffu + ((ua >> 16) & 1u);
  return (unsigned short)(ua >> 16);
}

// ---------------- fused prep: zero deg + x->bf16 + all weight converts ----------------
__global__ __launch_bounds__(256) void prep_k(
    const float4* __restrict__ x4, uint2* __restrict__ xb, int n4,
    const float* __restrict__ W1l, const float* __restrict__ W1r, u32* __restrict__ Wt1,
    const float* __restrict__ W2l, const float* __restrict__ W2r, u32* __restrict__ Wt2,
    const float* __restrict__ W3l, const float* __restrict__ W3r,
    u32* __restrict__ Wt3b, float* __restrict__ bias3b, const float* __restrict__ b3,
    int* __restrict__ deg, int N, int nbX)
{
  const int b = blockIdx.x;
  const int tid = threadIdx.x;
  if (b < nbX){
    int i = b * 256 + tid;
    if (i < n4){
      float4 v = x4[i];
      xb[i] = make_uint2(pack2bf(v.x, v.y), pack2bf(v.z, v.w));
    }
  } else if (b < nbX + 128){
    const bool first = (b < nbX + 64);
    const float* Wl = first ? W1l : W2l;
    const float* Wr = first ? W1r : W2r;
    u32* Wt = first ? Wt1 : Wt2;
    int i = ((b - nbX) & 63) * 256 + tid;         // 0..16383
    int nn = i >> 7, kp = i & 127;
    int k = kp * 2;
    float a, c;
    if (k < 128){ a = Wl[(size_t)k * 128 + nn]; c = Wl[(size_t)(k + 1) * 128 + nn]; }
    else        { a = Wr[(size_t)(k - 128) * 128 + nn]; c = Wr[(size_t)(k - 127) * 128 + nn]; }
    Wt[(size_t)nn * 128 + kp] = pack2bf(a, c);
  } else if (b < nbX + 160){
    // Wt3b[128 out][64 u32 k], K=128: out 0..39 = W3l^T, 64..103 = W3r^T, else 0
    int i = (b - nbX - 128) * 256 + tid;          // 0..8191
    if (i < 128 * 64){
      int nn = i >> 6, kp = i & 63;
      int k = kp * 2;
      float a = 0.f, c = 0.f;
      if (nn < NCLS){
        a = W3l[(size_t)k * NCLS + nn]; c = W3l[(size_t)(k + 1) * NCLS + nn];
      } else if (nn >= 64 && nn < 64 + NCLS){
        int cc = nn - 64;
        a = W3r[(size_t)k * NCLS + cc]; c = W3r[(size_t)(k + 1) * NCLS + cc];
      }
      Wt3b[(size_t)nn * 64 + kp] = pack2bf(a, c);
    }
    if (b == nbX + 128 && tid < 128)
      bias3b[tid] = (tid >= 64 && tid < 64 + NCLS) ? b3[tid - 64] : 0.f;
  } else {
    int i = (b - nbX - 160) * 256 + tid;
    if (i < N) deg[i] = 0;
  }
}

// ---------------- CSR build: chain-free LDS radix partition ----------------

// P1a: per-block bucket histogram (LDS) + fused global degree count
__global__ __launch_bounds__(256) void part_hist_k(
    const int* __restrict__ dst, int* __restrict__ deg,
    int* __restrict__ gcnt, int E, int nbuk)
{
  __shared__ int cnt[1024];
  const int tid = threadIdx.x;
  for (int i = tid; i < nbuk; i += 256) cnt[i] = 0;
  __syncthreads();
  const int per = (E + NBLK_P1 - 1) / NBLK_P1;
  const int e0 = blockIdx.x * per;
  const int e1 = min(e0 + per, E);
  for (int i = e0 + tid; i < e1; i += 256){
    int d = dst[i];
    atomicAdd(&deg[d], 1);
    atomicAdd(&cnt[d >> 7], 1);
  }
  __syncthreads();
  for (int i = tid; i < nbuk; i += 256)
    gcnt[(size_t)blockIdx.x * nbuk + i] = cnt[i];
}

__global__ void scan_excl_k(const int* __restrict__ in, int* __restrict__ out,
                            int* __restrict__ bsum, int n){
  __shared__ int sm[1024];
  int tid = threadIdx.x;
  int i = blockIdx.x * blockDim.x + tid;
  int v = (i < n) ? in[i] : 0;
  sm[tid] = v; __syncthreads();
  int acc = v;
  for (int off = 1; off < (int)blockDim.x; off <<= 1){
    int t = (tid >= off) ? sm[tid - off] : 0;
    __syncthreads();
    acc += t; sm[tid] = acc;
    __syncthreads();
  }
  if (i < n) out[i] = acc - v;
  if (bsum && tid == (int)blockDim.x - 1) bsum[blockIdx.x] = acc;
}

__global__ void finalize_k(int* __restrict__ csr_off, const int* __restrict__ bsum_s,
                           const int* __restrict__ deg, float* __restrict__ deg_inv,
                           int n, int E){
  int i = blockIdx.x * blockDim.x + threadIdx.x;
  if (i < n){
    csr_off[i] += bsum_s[i >> 10];
    deg_inv[i] = 1.0f / fmaxf((float)deg[i], 1.0f);
  }
  if (i == 0) csr_off[n] = E;
}

// P1s: per-bucket exclusive scan over the NBLK_P1 block counts (no contention)
__global__ __launch_bounds__(256) void part_scan_k(
    const int* __restrict__ csr_off, const int* __restrict__ gcnt,
    int* __restrict__ goff, int N, int nbuk)
{
  int j = blockIdx.x * 256 + threadIdx.x;
  if (j >= nbuk) return;
  int acc = csr_off[min(j << 7, N)];   // bucket base in csr/staging space
  for (int i = 0; i < NBLK_P1; i++){
    int t = gcnt[(size_t)i * nbuk + j];
    goff[(size_t)i * nbuk + j] = acc;
    acc += t;
  }
}

// P1b: scatter edges into bucket staging; entry = (src<<7)|dst_local (4B; needs N < 2^25)
__global__ __launch_bounds__(256) void part_fill_k(
    const int* __restrict__ src, const int* __restrict__ dst,
    const int* __restrict__ goff, u32* __restrict__ staging,
    int E, int nbuk)
{
  __shared__ int boff[1024];
  __shared__ int cur[1024];
  const int tid = threadIdx.x;
  for (int i = tid; i < nbuk; i += 256){
    boff[i] = goff[(size_t)blockIdx.x * nbuk + i];
    cur[i] = 0;
  }
  __syncthreads();
  const int per = (E + NBLK_P1 - 1) / NBLK_P1;
  const int e0 = blockIdx.x * per;
  const int e1 = min(e0 + per, E);
  for (int i = e0 + tid; i < e1; i += 256){
    int d = dst[i];
    int s = src[i];
    int b = d >> 7;
    int p = atomicAdd(&cur[b], 1);
    staging[boff[b] + p] = ((u32)s << 7) | (u32)(d & 127);
  }
}

// P2: one block per bucket; contiguous staging read, stores confined to ~8KB csr window
__global__ __launch_bounds__(256) void bucket_csr_k(
    const u32* __restrict__ staging, const int* __restrict__ coff,
    int* __restrict__ csr_src, int N)
{
  __shared__ int lpos[128];
  __shared__ int lbase[129];
  const int node0 = blockIdx.x << 7;
  const int tid = threadIdx.x;
  if (tid < 128) lpos[tid] = 0;
  if (tid < 129) lbase[tid] = coff[min(node0 + tid, N)];
  __syncthreads();
  const int lo = lbase[0], hi = lbase[128];
  for (int i = lo + tid; i < hi; i += 256){
    u32 v = staging[i];
    int dloc = (int)(v & 127u);
    int p = atomicAdd(&lpos[dloc], 1);
    csr_src[lbase[dloc] + p] = (int)(v >> 7);
  }
}

// ---------------- mean aggregation (bf16 gather via CSR), 4-way unrolled ----------------
__device__ inline void add8(float* acc, uint4 v){
  acc[0] += bflo(v.x); acc[1] += bfhi(v.x);
  acc[2] += bflo(v.y); acc[3] += bfhi(v.y);
  acc[4] += bflo(v.z); acc[5] += bfhi(v.z);
  acc[6] += bflo(v.w); acc[7] += bfhi(v.w);
}

__global__ __launch_bounds__(256) void aggregate_k(
    const u32* __restrict__ feat, const int* __restrict__ coff,
    const int* __restrict__ csr_src, const float* __restrict__ deg_inv,
    u32* __restrict__ agg, int n)
{
  const int g = threadIdx.x >> 4;
  const int lane = threadIdx.x & 15;
  const int node = blockIdx.x * 16 + g;
  if (node >= n) return;
  const int lo = coff[node], hi = coff[node + 1];
  const uint4* __restrict__ f4 = (const uint4*)feat;
  float acc[8] = {0.f,0.f,0.f,0.f,0.f,0.f,0.f,0.f};
  int e = lo;
  for (; e + 3 < hi; e += 4){
    int s0 = csr_src[e], s1 = csr_src[e + 1];
    int s2 = csr_src[e + 2], s3 = csr_src[e + 3];
    uint4 v0 = f4[(size_t)s0 * 16 + lane];
    uint4 v1 = f4[(size_t)s1 * 16 + lane];
    uint4 v2 = f4[(size_t)s2 * 16 + lane];
    uint4 v3 = f4[(size_t)s3 * 16 + lane];
    add8(acc, v0); add8(acc, v1); add8(acc, v2); add8(acc, v3);
  }
  for (; e < hi; ++e){
    uint4 v0 = f4[(size_t)csr_src[e] * 16 + lane];
    add8(acc, v0);
  }
  const float di = deg_inv[node];
  uint4 o;
  o.x = pack2bf(acc[0] * di, acc[1] * di);
  o.y = pack2bf(acc[2] * di, acc[3] * di);
  o.z = pack2bf(acc[4] * di, acc[5] * di);
  o.w = pack2bf(acc[6] * di, acc[7] * di);
  ((uint4*)agg)[(size_t)node * 16 + lane] = o;
}

// ---------------- MFMA dense: out = relu([A1|A2] @ Wt^T + bias), bf16, K=256 ----------------
__global__ __launch_bounds__(256) void gemm_mfma_k(
    const u32* __restrict__ A1, const u32* __restrict__ A2,
    const u32* __restrict__ Wt, const float* __restrict__ bias,
    u32* __restrict__ out, int n)
{
  __shared__ u32 As_u[128 * 20];   // row stride 20 u32 = 40 bf16
  __shared__ u32 Bs_u[128 * 20];
  const int tid = threadIdx.x;
  const int row0 = blockIdx.x * 128;
  const int l = tid & 63, w = tid >> 6;
  const int lm = l & 15, lq = l >> 4;

  f32x4 acc[2][8];
  #pragma unroll
  for (int mi = 0; mi < 2; mi++)
    #pragma unroll
    for (int ni = 0; ni < 8; ni++) acc[mi][ni] = (f32x4){0.f, 0.f, 0.f, 0.f};

  for (int kt = 0; kt < 8; ++kt){
    const u32* Ap = (kt < 4) ? A1 : A2;
    const int ko = (kt & 3) * 16;
    #pragma unroll
    for (int i = 0; i < 2; i++){
      int chunk = tid + 256 * i;
      int row = chunk >> 2, q = chunk & 3;
      uint4 av = make_uint4(0, 0, 0, 0);
      int gr = row0 + row;
      if (gr < n) av = *(const uint4*)(Ap + (size_t)gr * 64 + ko + q * 4);
      *(uint4*)&As_u[row * 20 + q * 4] = av;
      uint4 bv = *(const uint4*)(Wt + (size_t)row * 128 + kt * 16 + q * 4);
      *(uint4*)&Bs_u[row * 20 + q * 4] = bv;
    }
    __syncthreads();
    short8 af0 = *(const short8*)&As_u[(w * 32 + lm) * 20 + lq * 4];
    short8 af1 = *(const short8*)&As_u[(w * 32 + 16 + lm) * 20 + lq * 4];
    #pragma unroll
    for (int ni = 0; ni < 8; ni++){
      short8 bf = *(const short8*)&Bs_u[(ni * 16 + lm) * 20 + lq * 4];
      acc[0][ni] = __builtin_amdgcn_mfma_f32_16x16x32_bf16(af0, bf, acc[0][ni], 0, 0, 0);
      acc[1][ni] = __builtin_amdgcn_mfma_f32_16x16x32_bf16(af1, bf, acc[1][ni], 0, 0, 0);
    }
    __syncthreads();
  }

  float bb[8];
  #pragma unroll
  for (int ni = 0; ni < 8; ni++) bb[ni] = bias[ni * 16 + lm];
  unsigned short* outp = (unsigned short*)out;
  #pragma unroll
  for (int mi = 0; mi < 2; mi++){
    #pragma unroll
    for (int r = 0; r < 4; r++){
      int row = row0 + w * 32 + mi * 16 + lq * 4 + r;
      if (row < n){
        #pragma unroll
        for (int ni = 0; ni < 8; ni++){
          float v = fmaxf(acc[mi][ni][r] + bb[ni], 0.f);
          outp[(size_t)row * 128 + ni * 16 + lm] = pack1bf(v);
        }
      }
    }
  }
}

// ---------------- layer-3 pre-GEMM (K=128, no relu): yz = h @ Wt3b^T + bias3b ----------------
__global__ __launch_bounds__(256) void gemm3_mfma_k(
    const u32* __restrict__ A, const u32* __restrict__ Wt3b,
    const float* __restrict__ bias, u32* __restrict__ out, int n)
{
  __shared__ u32 As_u[128 * 20];
  __shared__ u32 Bs_u[128 * 20];
  const int tid = threadIdx.x;
  const int row0 = blockIdx.x * 128;
  const int l = tid & 63, w = tid >> 6;
  const int lm = l & 15, lq = l >> 4;

  f32x4 acc[2][8];
  #pragma unroll
  for (int mi = 0; mi < 2; mi++)
    #pragma unroll
    for (int ni = 0; ni < 8; ni++) acc[mi][ni] = (f32x4){0.f, 0.f, 0.f, 0.f};

  for (int kt = 0; kt < 4; ++kt){
    #pragma unroll
    for (int i = 0; i < 2; i++){
      int chunk = tid + 256 * i;
      int row = chunk >> 2, q = chunk & 3;
      uint4 av = make_uint4(0, 0, 0, 0);
      int gr = row0 + row;
      if (gr < n) av = *(const uint4*)(A + (size_t)gr * 64 + kt * 16 + q * 4);
      *(uint4*)&As_u[row * 20 + q * 4] = av;
      uint4 bv = *(const uint4*)(Wt3b + (size_t)row * 64 + kt * 16 + q * 4);
      *(uint4*)&Bs_u[row * 20 + q * 4] = bv;
    }
    __syncthreads();
    short8 af0 = *(const short8*)&As_u[(w * 32 + lm) * 20 + lq * 4];
    short8 af1 = *(const short8*)&As_u[(w * 32 + 16 + lm) * 20 + lq * 4];
    #pragma unroll
    for (int ni = 0; ni < 8; ni++){
      short8 bf = *(const short8*)&Bs_u[(ni * 16 + lm) * 20 + lq * 4];
      acc[0][ni] = __builtin_amdgcn_mfma_f32_16x16x32_bf16(af0, bf, acc[0][ni], 0, 0, 0);
      acc[1][ni] = __builtin_amdgcn_mfma_f32_16x16x32_bf16(af1, bf, acc[1][ni], 0, 0, 0);
    }
    __syncthreads();
  }

  float bb[8];
  #pragma unroll
  for (int ni = 0; ni < 8; ni++) bb[ni] = bias[ni * 16 + lm];
  unsigned short* outp = (unsigned short*)out;
  #pragma unroll
  for (int mi = 0; mi < 2; mi++){
    #pragma unroll
    for (int r = 0; r < 4; r++){
      int row = row0 + w * 32 + mi * 16 + lq * 4 + r;
      if (row < n){
        #pragma unroll
        for (int ni = 0; ni < 8; ni++){
          float v = acc[mi][ni][r] + bb[ni];
          outp[(size_t)row * 128 + ni * 16 + lm] = pack1bf(v);
        }
      }
    }
  }
}

// ---------------- fused: out = log_softmax(mean-gather(y) + z) ----------------
__global__ __launch_bounds__(256) void agg_softmax_k(
    const u32* __restrict__ yz, const int* __restrict__ coff,
    const int* __restrict__ csr_src, const float* __restrict__ deg_inv,
    float* __restrict__ out, int n)
{
  const int g = threadIdx.x >> 3;
  const int lane = threadIdx.x & 7;
  const int node = blockIdx.x * 32 + g;
  if (node >= n) return;
  const int lo = coff[node], hi = coff[node + 1];
  const uint4* __restrict__ f4 = (const uint4*)yz;    // 16 uint4 per row; y = first 8
  float acc[8] = {0.f,0.f,0.f,0.f,0.f,0.f,0.f,0.f};
  int e = lo;
  for (; e + 3 < hi; e += 4){
    int s0 = csr_src[e], s1 = csr_src[e + 1];
    int s2 = csr_src[e + 2], s3 = csr_src[e + 3];
    uint4 v0 = f4[(size_t)s0 * 16 + lane];
    uint4 v1 = f4[(size_t)s1 * 16 + lane];
    uint4 v2 = f4[(size_t)s2 * 16 + lane];
    uint4 v3 = f4[(size_t)s3 * 16 + lane];
    add8(acc, v0); add8(acc, v1); add8(acc, v2); add8(acc, v3);
  }
  for (; e < hi; ++e){
    uint4 v0 = f4[(size_t)csr_src[e] * 16 + lane];
    add8(acc, v0);
  }
  const float di = deg_inv[node];
  uint4 zv = f4[(size_t)node * 16 + 8 + lane];
  float v[8];
  v[0] = acc[0] * di + bflo(zv.x); v[1] = acc[1] * di + bfhi(zv.x);
  v[2] = acc[2] * di + bflo(zv.y); v[3] = acc[3] * di + bfhi(zv.y);
  v[4] = acc[4] * di + bflo(zv.z); v[5] = acc[5] * di + bfhi(zv.z);
  v[6] = acc[6] * di + bflo(zv.w); v[7] = acc[7] * di + bfhi(zv.w);
  const bool valid = (lane < 5);
  float m = -INFINITY;
  if (valid){
    #pragma unroll
    for (int j = 0; j < 8; j++) m = fmaxf(m, v[j]);
  }
  #pragma unroll
  for (int off = 1; off < 8; off <<= 1) m = fmaxf(m, __shfl_xor(m, off, 64));
  float s = 0.f;
  if (valid){
    #pragma unroll
    for (int j = 0; j < 8; j++) s += __expf(v[j] - m);
  }
  #pragma unroll
  for (int off = 1; off < 8; off <<= 1) s += __shfl_xor(s, off, 64);
  const float ls = m + logf(s);
  if (valid){
    float* op = out + (size_t)node * NCLS + lane * 8;
    *(float4*)op     = make_float4(v[0]-ls, v[1]-ls, v[2]-ls, v[3]-ls);
    *(float4*)(op+4) = make_float4(v[4]-ls, v[5]-ls, v[6]-ls, v[7]-ls);
  }
}

// ---------------- launch ----------------

extern "C" void kernel_launch(void* const* d_in, const int* in_sizes, int n_in,
                              void* d_out, int out_size, void* d_ws, size_t ws_size,
                              hipStream_t stream) {
  const float* x   = (const float*)d_in[0];
  const int*   ei  = (const int*)d_in[1];
  const float* W1l = (const float*)d_in[2];
  const float* b1  = (const float*)d_in[3];
  const float* W1r = (const float*)d_in[4];
  const float* W2l = (const float*)d_in[5];
  const float* b2  = (const float*)d_in[6];
  const float* W2r = (const float*)d_in[7];
  const float* W3l = (const float*)d_in[8];
  const float* b3  = (const float*)d_in[9];
  const float* W3r = (const float*)d_in[10];

  const int N = in_sizes[0] / D;       // 100000
  const int E = in_sizes[1] / 2;       // 1600000
  const int* src = ei;
  const int* dst = ei + E;
  const int nbuk = (N + 127) >> 7;     // 782 buckets of 128 nodes

  char* ws = (char*)d_ws;
  auto alloc = [&](size_t bytes) -> void* {
    void* p = (void*)ws;
    ws += (bytes + 255) & ~(size_t)255;
    return p;
  };
  int*   deg_i    = (int*)  alloc((size_t)N * 4);
  int*   csr_off  = (int*)  alloc((size_t)(N + 1) * 4);
  int*   bsum     = (int*)  alloc(1024);
  int*   bsum_s   = (int*)  alloc(1024);
  float* deg_inv  = (float*)alloc((size_t)N * 4);
  int*   csr_src  = (int*)  alloc((size_t)E * 4);
  u32*   staging  = (u32*)  alloc((size_t)E * 4);
  int*   gcnt     = (int*)  alloc((size_t)NBLK_P1 * nbuk * 4);
  int*   goff     = (int*)  alloc((size_t)NBLK_P1 * nbuk * 4);
  u32*   xb       = (u32*)  alloc((size_t)N * D * 2);
  u32*   agg      = (u32*)  alloc((size_t)N * D * 2);
  u32*   hbuf     = (u32*)  alloc((size_t)N * D * 2);
  u32*   yz       = (u32*)  alloc((size_t)N * D * 2);
  u32*   Wt1      = (u32*)  alloc((size_t)128 * 128 * 4);
  u32*   Wt2      = (u32*)  alloc((size_t)128 * 128 * 4);
  u32*   Wt3b     = (u32*)  alloc((size_t)128 * 64 * 4);
  float* bias3b   = (float*)alloc((size_t)128 * 4);

  // fused prep: x->bf16, weight converts, zero deg
  const int n4 = N * D / 4;
  const int nbX = (n4 + 255) / 256;
  const int nbZ = (N + 255) / 256;
  prep_k<<<nbX + 160 + nbZ, 256, 0, stream>>>(
      (const float4*)x, (uint2*)xb, n4,
      W1l, W1r, Wt1, W2l, W2r, Wt2,
      W3l, W3r, Wt3b, bias3b, b3,
      deg_i, N, nbX);

  // CSR build: histogram (+deg) -> node scan -> bucket-block scan -> partition -> bucket fill
  part_hist_k<<<NBLK_P1, 256, 0, stream>>>(dst, deg_i, gcnt, E, nbuk);
  const int NB = (N + 1023) / 1024;
  scan_excl_k<<<NB, 1024, 0, stream>>>(deg_i, csr_off, bsum, N);
  scan_excl_k<<<1, 128, 0, stream>>>(bsum, bsum_s, nullptr, NB);
  finalize_k<<<(N + 255) / 256, 256, 0, stream>>>(csr_off, bsum_s, deg_i, deg_inv, N, E);
  part_scan_k<<<(nbuk + 255) / 256, 256, 0, stream>>>(csr_off, gcnt, goff, N, nbuk);
  part_fill_k<<<NBLK_P1, 256, 0, stream>>>(src, dst, goff, staging, E, nbuk);
  bucket_csr_k<<<nbuk, 256, 0, stream>>>(staging, csr_off, csr_src, N);

  const int gblocks = (N + 127) / 128;
  const int ablocks = (N + 15) / 16;
  // layer 1
  aggregate_k<<<ablocks, 256, 0, stream>>>(xb, csr_off, csr_src, deg_inv, agg, N);
  gemm_mfma_k<<<gblocks, 256, 0, stream>>>(agg, xb, Wt1, b1, hbuf, N);
  // layer 2
  aggregate_k<<<ablocks, 256, 0, stream>>>(hbuf, csr_off, csr_src, deg_inv, agg, N);
  gemm_mfma_k<<<gblocks, 256, 0, stream>>>(agg, hbuf, Wt2, b2, hbuf, N);
  // layer 3: yz = h@[W3l|W3r]+b (K=128), then fused mean-gather + log_softmax
  gemm3_mfma_k<<<gblocks, 256, 0, stream>>>(hbuf, Wt3b, bias3b, yz, N);
  agg_softmax_k<<<(N + 31) / 32, 256, 0, stream>>>(yz, csr_off, csr_src, deg_inv,
                                                   (float*)d_out, N);
}

// Round 10
// 409.246 us; speedup vs baseline: 1.1651x; 1.1234x over previous
//
#include <hip/hip_runtime.h>
#include <math.h>

#define D 128
#define NCLS 40
#define NBLK_P1 256      // partition blocks; bucket = 128 nodes, nbuk <= 1024

typedef unsigned int u32;
typedef __attribute__((ext_vector_type(8))) short short8;
typedef __attribute__((ext_vector_type(4))) float f32x4;

__device__ inline float bflo(u32 u){ return __uint_as_float(u << 16); }
__device__ inline float bfhi(u32 u){ return __uint_as_float(u & 0xffff0000u); }
__device__ inline u32 pack2bf(float a, float b){
  u32 ua = __float_as_uint(a), ub = __float_as_uint(b);
  ua += 0x7fffu + ((ua >> 16) & 1u);
  ub += 0x7fffu + ((ub >> 16) & 1u);
  return (ua >> 16) | (ub & 0xffff0000u);
}
__device__ inline unsigned short pack1bf(float a){
  u32 ua = __float_as_uint(a);
  ua += 0x7fffu + ((ua >> 16) & 1u);
  return (unsigned short)(ua >> 16);
}

// ---------------- fused prep: x->bf16 + all weight converts ----------------
__global__ __launch_bounds__(256) void prep_k(
    const float4* __restrict__ x4, uint2* __restrict__ xb, int n4,
    const float* __restrict__ W1l, const float* __restrict__ W1r, u32* __restrict__ Wt1,
    const float* __restrict__ W2l, const float* __restrict__ W2r, u32* __restrict__ Wt2,
    const float* __restrict__ W3l, const float* __restrict__ W3r,
    u32* __restrict__ Wt3b, float* __restrict__ bias3b, const float* __restrict__ b3,
    int nbX)
{
  const int b = blockIdx.x;
  const int tid = threadIdx.x;
  if (b < nbX){
    int i = b * 256 + tid;
    if (i < n4){
      float4 v = x4[i];
      xb[i] = make_uint2(pack2bf(v.x, v.y), pack2bf(v.z, v.w));
    }
  } else if (b < nbX + 128){
    const bool first = (b < nbX + 64);
    const float* Wl = first ? W1l : W2l;
    const float* Wr = first ? W1r : W2r;
    u32* Wt = first ? Wt1 : Wt2;
    int i = ((b - nbX) & 63) * 256 + tid;         // 0..16383
    int nn = i >> 7, kp = i & 127;
    int k = kp * 2;
    float a, c;
    if (k < 128){ a = Wl[(size_t)k * 128 + nn]; c = Wl[(size_t)(k + 1) * 128 + nn]; }
    else        { a = Wr[(size_t)(k - 128) * 128 + nn]; c = Wr[(size_t)(k - 127) * 128 + nn]; }
    Wt[(size_t)nn * 128 + kp] = pack2bf(a, c);
  } else {
    // Wt3b[128 out][64 u32 k], K=128: out 0..39 = W3l^T, 64..103 = W3r^T, else 0
    int i = (b - nbX - 128) * 256 + tid;          // 0..8191
    if (i < 128 * 64){
      int nn = i >> 6, kp = i & 63;
      int k = kp * 2;
      float a = 0.f, c = 0.f;
      if (nn < NCLS){
        a = W3l[(size_t)k * NCLS + nn]; c = W3l[(size_t)(k + 1) * NCLS + nn];
      } else if (nn >= 64 && nn < 64 + NCLS){
        int cc = nn - 64;
        a = W3r[(size_t)k * NCLS + cc]; c = W3r[(size_t)(k + 1) * NCLS + cc];
      }
      Wt3b[(size_t)nn * 64 + kp] = pack2bf(a, c);
    }
    if (b == nbX + 128 && tid < 128)
      bias3b[tid] = (tid >= 64 && tid < 64 + NCLS) ? b3[tid - 64] : 0.f;
  }
}

// ---------------- CSR build: chain-free LDS radix partition, no global deg ----------------

// P1a: per-block bucket histogram (LDS only)
__global__ __launch_bounds__(256) void part_hist_k(
    const int* __restrict__ dst, int* __restrict__ gcnt, int E, int nbuk)
{
  __shared__ int cnt[1024];
  const int tid = threadIdx.x;
  for (int i = tid; i < nbuk; i += 256) cnt[i] = 0;
  __syncthreads();
  const int per = (E + NBLK_P1 - 1) / NBLK_P1;
  const int e0 = blockIdx.x * per;
  const int e1 = min(e0 + per, E);
  for (int i = e0 + tid; i < e1; i += 256)
    atomicAdd(&cnt[dst[i] >> 7], 1);
  __syncthreads();
  for (int i = tid; i < nbuk; i += 256)
    gcnt[(size_t)blockIdx.x * nbuk + i] = cnt[i];
}

// P1s: bucket totals -> exclusive bucket bases (bbase) + per-block offsets (goff)
__global__ __launch_bounds__(1024) void part_scan_k(
    const int* __restrict__ gcnt, int* __restrict__ goff,
    int* __restrict__ bbase, int nbuk)
{
  __shared__ int sm[1024];
  const int j = threadIdx.x;
  int btot = 0;
  if (j < nbuk)
    for (int i = 0; i < NBLK_P1; i++) btot += gcnt[(size_t)i * nbuk + j];
  sm[j] = btot;
  __syncthreads();
  int acc = btot;
  for (int off = 1; off < 1024; off <<= 1){
    int t = (j >= off) ? sm[j - off] : 0;
    __syncthreads();
    acc += t; sm[j] = acc;
    __syncthreads();
  }
  const int base = acc - btot;       // exclusive
  if (j < nbuk){
    bbase[j] = base;
    if (j == nbuk - 1) bbase[nbuk] = base + btot;   // == E
    int run = base;
    for (int i = 0; i < NBLK_P1; i++){
      goff[(size_t)i * nbuk + j] = run;
      run += gcnt[(size_t)i * nbuk + j];
    }
  }
}

// P1b: scatter edges into bucket staging; entry = (src<<7)|dst_local (4B; needs src < 2^25)
__global__ __launch_bounds__(256) void part_fill_k(
    const int* __restrict__ src, const int* __restrict__ dst,
    const int* __restrict__ goff, u32* __restrict__ staging,
    int E, int nbuk)
{
  __shared__ int boff[1024];
  __shared__ int cur[1024];
  const int tid = threadIdx.x;
  for (int i = tid; i < nbuk; i += 256){
    boff[i] = goff[(size_t)blockIdx.x * nbuk + i];
    cur[i] = 0;
  }
  __syncthreads();
  const int per = (E + NBLK_P1 - 1) / NBLK_P1;
  const int e0 = blockIdx.x * per;
  const int e1 = min(e0 + per, E);
  for (int i = e0 + tid; i < e1; i += 256){
    int d = dst[i];
    int s = src[i];
    int b = d >> 7;
    int p = atomicAdd(&cur[b], 1);
    staging[boff[b] + p] = ((u32)s << 7) | (u32)(d & 127);
  }
}

// P2: one block per bucket. LDS degree histogram -> local scan -> csr_off/deg_inv,
// then ordered csr_src scatter confined to the bucket's ~contiguous window.
__global__ __launch_bounds__(256) void bucket_csr_k(
    const u32* __restrict__ staging, const int* __restrict__ bbase,
    int* __restrict__ csr_off, float* __restrict__ deg_inv,
    int* __restrict__ csr_src, int N)
{
  __shared__ int ldeg[128];
  __shared__ int sm[128];
  __shared__ int lbase[128];
  __shared__ int lpos[128];
  const int b = blockIdx.x;
  const int node0 = b << 7;
  const int tid = threadIdx.x;
  if (tid < 128) ldeg[tid] = 0;
  __syncthreads();
  const int lo = bbase[b], hi = bbase[b + 1];
  for (int i = lo + tid; i < hi; i += 256)
    atomicAdd(&ldeg[staging[i] & 127u], 1);
  __syncthreads();
  if (tid < 128) sm[tid] = ldeg[tid];
  __syncthreads();
  for (int off = 1; off < 128; off <<= 1){
    int t = (tid >= off && tid < 128) ? sm[tid - off] : 0;
    __syncthreads();
    if (tid < 128) sm[tid] += t;
    __syncthreads();
  }
  if (tid < 128){
    const int excl = sm[tid] - ldeg[tid];
    lbase[tid] = lo + excl;
    lpos[tid] = 0;
    const int node = node0 + tid;
    if (node < N){
      csr_off[node] = lo + excl;
      deg_inv[node] = 1.0f / fmaxf((float)ldeg[tid], 1.0f);
    } else if (node == N){
      csr_off[N] = lo + excl;        // == E (no edges beyond N)
    }
  }
  if (tid == 0 && b == (int)gridDim.x - 1) csr_off[N] = hi;   // covers N%128==0
  __syncthreads();
  for (int i = lo + tid; i < hi; i += 256){
    u32 v = staging[i];
    int dloc = (int)(v & 127u);
    int p = atomicAdd(&lpos[dloc], 1);
    csr_src[lbase[dloc] + p] = (int)(v >> 7);
  }
}

// ---------------- mean aggregation (bf16 gather via CSR), 4-way unrolled ----------------
__device__ inline void add8(float* acc, uint4 v){
  acc[0] += bflo(v.x); acc[1] += bfhi(v.x);
  acc[2] += bflo(v.y); acc[3] += bfhi(v.y);
  acc[4] += bflo(v.z); acc[5] += bfhi(v.z);
  acc[6] += bflo(v.w); acc[7] += bfhi(v.w);
}

__global__ __launch_bounds__(256) void aggregate_k(
    const u32* __restrict__ feat, const int* __restrict__ coff,
    const int* __restrict__ csr_src, const float* __restrict__ deg_inv,
    u32* __restrict__ agg, int n)
{
  const int g = threadIdx.x >> 4;
  const int lane = threadIdx.x & 15;
  const int node = blockIdx.x * 16 + g;
  if (node >= n) return;
  const int lo = coff[node], hi = coff[node + 1];
  const uint4* __restrict__ f4 = (const uint4*)feat;
  float acc[8] = {0.f,0.f,0.f,0.f,0.f,0.f,0.f,0.f};
  int e = lo;
  for (; e + 3 < hi; e += 4){
    int s0 = csr_src[e], s1 = csr_src[e + 1];
    int s2 = csr_src[e + 2], s3 = csr_src[e + 3];
    uint4 v0 = f4[(size_t)s0 * 16 + lane];
    uint4 v1 = f4[(size_t)s1 * 16 + lane];
    uint4 v2 = f4[(size_t)s2 * 16 + lane];
    uint4 v3 = f4[(size_t)s3 * 16 + lane];
    add8(acc, v0); add8(acc, v1); add8(acc, v2); add8(acc, v3);
  }
  for (; e < hi; ++e){
    uint4 v0 = f4[(size_t)csr_src[e] * 16 + lane];
    add8(acc, v0);
  }
  const float di = deg_inv[node];
  uint4 o;
  o.x = pack2bf(acc[0] * di, acc[1] * di);
  o.y = pack2bf(acc[2] * di, acc[3] * di);
  o.z = pack2bf(acc[4] * di, acc[5] * di);
  o.w = pack2bf(acc[6] * di, acc[7] * di);
  ((uint4*)agg)[(size_t)node * 16 + lane] = o;
}

// ---------------- MFMA dense: out = relu([A1|A2] @ Wt^T + bias), bf16, K=256 ----------------
__global__ __launch_bounds__(256) void gemm_mfma_k(
    const u32* __restrict__ A1, const u32* __restrict__ A2,
    const u32* __restrict__ Wt, const float* __restrict__ bias,
    u32* __restrict__ out, int n)
{
  __shared__ u32 As_u[128 * 20];   // row stride 20 u32 = 40 bf16
  __shared__ u32 Bs_u[128 * 20];
  const int tid = threadIdx.x;
  const int row0 = blockIdx.x * 128;
  const int l = tid & 63, w = tid >> 6;
  const int lm = l & 15, lq = l >> 4;

  f32x4 acc[2][8];
  #pragma unroll
  for (int mi = 0; mi < 2; mi++)
    #pragma unroll
    for (int ni = 0; ni < 8; ni++) acc[mi][ni] = (f32x4){0.f, 0.f, 0.f, 0.f};

  for (int kt = 0; kt < 8; ++kt){
    const u32* Ap = (kt < 4) ? A1 : A2;
    const int ko = (kt & 3) * 16;
    #pragma unroll
    for (int i = 0; i < 2; i++){
      int chunk = tid + 256 * i;
      int row = chunk >> 2, q = chunk & 3;
      uint4 av = make_uint4(0, 0, 0, 0);
      int gr = row0 + row;
      if (gr < n) av = *(const uint4*)(Ap + (size_t)gr * 64 + ko + q * 4);
      *(uint4*)&As_u[row * 20 + q * 4] = av;
      uint4 bv = *(const uint4*)(Wt + (size_t)row * 128 + kt * 16 + q * 4);
      *(uint4*)&Bs_u[row * 20 + q * 4] = bv;
    }
    __syncthreads();
    short8 af0 = *(const short8*)&As_u[(w * 32 + lm) * 20 + lq * 4];
    short8 af1 = *(const short8*)&As_u[(w * 32 + 16 + lm) * 20 + lq * 4];
    #pragma unroll
    for (int ni = 0; ni < 8; ni++){
      short8 bf = *(const short8*)&Bs_u[(ni * 16 + lm) * 20 + lq * 4];
      acc[0][ni] = __builtin_amdgcn_mfma_f32_16x16x32_bf16(af0, bf, acc[0][ni], 0, 0, 0);
      acc[1][ni] = __builtin_amdgcn_mfma_f32_16x16x32_bf16(af1, bf, acc[1][ni], 0, 0, 0);
    }
    __syncthreads();
  }

  float bb[8];
  #pragma unroll
  for (int ni = 0; ni < 8; ni++) bb[ni] = bias[ni * 16 + lm];
  unsigned short* outp = (unsigned short*)out;
  #pragma unroll
  for (int mi = 0; mi < 2; mi++){
    #pragma unroll
    for (int r = 0; r < 4; r++){
      int row = row0 + w * 32 + mi * 16 + lq * 4 + r;
      if (row < n){
        #pragma unroll
        for (int ni = 0; ni < 8; ni++){
          float v = fmaxf(acc[mi][ni][r] + bb[ni], 0.f);
          outp[(size_t)row * 128 + ni * 16 + lm] = pack1bf(v);
        }
      }
    }
  }
}

// ---------------- layer-3 pre-GEMM (K=128, no relu): yz = h @ Wt3b^T + bias3b ----------------
__global__ __launch_bounds__(256) void gemm3_mfma_k(
    const u32* __restrict__ A, const u32* __restrict__ Wt3b,
    const float* __restrict__ bias, u32* __restrict__ out, int n)
{
  __shared__ u32 As_u[128 * 20];
  __shared__ u32 Bs_u[128 * 20];
  const int tid = threadIdx.x;
  const int row0 = blockIdx.x * 128;
  const int l = tid & 63, w = tid >> 6;
  const int lm = l & 15, lq = l >> 4;

  f32x4 acc[2][8];
  #pragma unroll
  for (int mi = 0; mi < 2; mi++)
    #pragma unroll
    for (int ni = 0; ni < 8; ni++) acc[mi][ni] = (f32x4){0.f, 0.f, 0.f, 0.f};

  for (int kt = 0; kt < 4; ++kt){
    #pragma unroll
    for (int i = 0; i < 2; i++){
      int chunk = tid + 256 * i;
      int row = chunk >> 2, q = chunk & 3;
      uint4 av = make_uint4(0, 0, 0, 0);
      int gr = row0 + row;
      if (gr < n) av = *(const uint4*)(A + (size_t)gr * 64 + kt * 16 + q * 4);
      *(uint4*)&As_u[row * 20 + q * 4] = av;
      uint4 bv = *(const uint4*)(Wt3b + (size_t)row * 64 + kt * 16 + q * 4);
      *(uint4*)&Bs_u[row * 20 + q * 4] = bv;
    }
    __syncthreads();
    short8 af0 = *(const short8*)&As_u[(w * 32 + lm) * 20 + lq * 4];
    short8 af1 = *(const short8*)&As_u[(w * 32 + 16 + lm) * 20 + lq * 4];
    #pragma unroll
    for (int ni = 0; ni < 8; ni++){
      short8 bf = *(const short8*)&Bs_u[(ni * 16 + lm) * 20 + lq * 4];
      acc[0][ni] = __builtin_amdgcn_mfma_f32_16x16x32_bf16(af0, bf, acc[0][ni], 0, 0, 0);
      acc[1][ni] = __builtin_amdgcn_mfma_f32_16x16x32_bf16(af1, bf, acc[1][ni], 0, 0, 0);
    }
    __syncthreads();
  }

  float bb[8];
  #pragma unroll
  for (int ni = 0; ni < 8; ni++) bb[ni] = bias[ni * 16 + lm];
  unsigned short* outp = (unsigned short*)out;
  #pragma unroll
  for (int mi = 0; mi < 2; mi++){
    #pragma unroll
    for (int r = 0; r < 4; r++){
      int row = row0 + w * 32 + mi * 16 + lq * 4 + r;
      if (row < n){
        #pragma unroll
        for (int ni = 0; ni < 8; ni++){
          float v = acc[mi][ni][r] + bb[ni];
          outp[(size_t)row * 128 + ni * 16 + lm] = pack1bf(v);
        }
      }
    }
  }
}

// ---------------- fused: out = log_softmax(mean-gather(y) + z) ----------------
__global__ __launch_bounds__(256) void agg_softmax_k(
    const u32* __restrict__ yz, const int* __restrict__ coff,
    const int* __restrict__ csr_src, const float* __restrict__ deg_inv,
    float* __restrict__ out, int n)
{
  const int g = threadIdx.x >> 3;
  const int lane = threadIdx.x & 7;
  const int node = blockIdx.x * 32 + g;
  if (node >= n) return;
  const int lo = coff[node], hi = coff[node + 1];
  const uint4* __restrict__ f4 = (const uint4*)yz;    // 16 uint4 per row; y = first 8
  float acc[8] = {0.f,0.f,0.f,0.f,0.f,0.f,0.f,0.f};
  int e = lo;
  for (; e + 3 < hi; e += 4){
    int s0 = csr_src[e], s1 = csr_src[e + 1];
    int s2 = csr_src[e + 2], s3 = csr_src[e + 3];
    uint4 v0 = f4[(size_t)s0 * 16 + lane];
    uint4 v1 = f4[(size_t)s1 * 16 + lane];
    uint4 v2 = f4[(size_t)s2 * 16 + lane];
    uint4 v3 = f4[(size_t)s3 * 16 + lane];
    add8(acc, v0); add8(acc, v1); add8(acc, v2); add8(acc, v3);
  }
  for (; e < hi; ++e){
    uint4 v0 = f4[(size_t)csr_src[e] * 16 + lane];
    add8(acc, v0);
  }
  const float di = deg_inv[node];
  uint4 zv = f4[(size_t)node * 16 + 8 + lane];
  float v[8];
  v[0] = acc[0] * di + bflo(zv.x); v[1] = acc[1] * di + bfhi(zv.x);
  v[2] = acc[2] * di + bflo(zv.y); v[3] = acc[3] * di + bfhi(zv.y);
  v[4] = acc[4] * di + bflo(zv.z); v[5] = acc[5] * di + bfhi(zv.z);
  v[6] = acc[6] * di + bflo(zv.w); v[7] = acc[7] * di + bfhi(zv.w);
  const bool valid = (lane < 5);
  float m = -INFINITY;
  if (valid){
    #pragma unroll
    for (int j = 0; j < 8; j++) m = fmaxf(m, v[j]);
  }
  #pragma unroll
  for (int off = 1; off < 8; off <<= 1) m = fmaxf(m, __shfl_xor(m, off, 64));
  float s = 0.f;
  if (valid){
    #pragma unroll
    for (int j = 0; j < 8; j++) s += __expf(v[j] - m);
  }
  #pragma unroll
  for (int off = 1; off < 8; off <<= 1) s += __shfl_xor(s, off, 64);
  const float ls = m + logf(s);
  if (valid){
    float* op = out + (size_t)node * NCLS + lane * 8;
    *(float4*)op     = make_float4(v[0]-ls, v[1]-ls, v[2]-ls, v[3]-ls);
    *(float4*)(op+4) = make_float4(v[4]-ls, v[5]-ls, v[6]-ls, v[7]-ls);
  }
}

// ---------------- launch ----------------

extern "C" void kernel_launch(void* const* d_in, const int* in_sizes, int n_in,
                              void* d_out, int out_size, void* d_ws, size_t ws_size,
                              hipStream_t stream) {
  const float* x   = (const float*)d_in[0];
  const int*   ei  = (const int*)d_in[1];
  const float* W1l = (const float*)d_in[2];
  const float* b1  = (const float*)d_in[3];
  const float* W1r = (const float*)d_in[4];
  const float* W2l = (const float*)d_in[5];
  const float* b2  = (const float*)d_in[6];
  const float* W2r = (const float*)d_in[7];
  const float* W3l = (const float*)d_in[8];
  const float* b3  = (const float*)d_in[9];
  const float* W3r = (const float*)d_in[10];

  const int N = in_sizes[0] / D;       // 100000
  const int E = in_sizes[1] / 2;       // 1600000
  const int* src = ei;
  const int* dst = ei + E;
  const int nbuk = (N + 127) >> 7;     // 782 buckets of 128 nodes

  char* ws = (char*)d_ws;
  auto alloc = [&](size_t bytes) -> void* {
    void* p = (void*)ws;
    ws += (bytes + 255) & ~(size_t)255;
    return p;
  };
  int*   csr_off  = (int*)  alloc((size_t)(N + 1) * 4);
  float* deg_inv  = (float*)alloc((size_t)N * 4);
  int*   csr_src  = (int*)  alloc((size_t)E * 4);
  u32*   staging  = (u32*)  alloc((size_t)E * 4);
  int*   gcnt     = (int*)  alloc((size_t)NBLK_P1 * nbuk * 4);
  int*   goff     = (int*)  alloc((size_t)NBLK_P1 * nbuk * 4);
  int*   bbase    = (int*)  alloc((size_t)(nbuk + 1) * 4);
  u32*   xb       = (u32*)  alloc((size_t)N * D * 2);
  u32*   agg      = (u32*)  alloc((size_t)N * D * 2);
  u32*   hbuf     = (u32*)  alloc((size_t)N * D * 2);
  u32*   yz       = (u32*)  alloc((size_t)N * D * 2);
  u32*   Wt1      = (u32*)  alloc((size_t)128 * 128 * 4);
  u32*   Wt2      = (u32*)  alloc((size_t)128 * 128 * 4);
  u32*   Wt3b    = (u32*)  alloc((size_t)128 * 64 * 4);
  float* bias3b   = (float*)alloc((size_t)128 * 4);

  // fused prep: x->bf16, weight converts
  const int n4 = N * D / 4;
  const int nbX = (n4 + 255) / 256;
  prep_k<<<nbX + 160, 256, 0, stream>>>(
      (const float4*)x, (uint2*)xb, n4,
      W1l, W1r, Wt1, W2l, W2r, Wt2,
      W3l, W3r, Wt3b, bias3b, b3, nbX);

  // CSR build: LDS histogram -> bucket scan -> partition -> per-bucket deg+scan+fill
  part_hist_k<<<NBLK_P1, 256, 0, stream>>>(dst, gcnt, E, nbuk);
  part_scan_k<<<1, 1024, 0, stream>>>(gcnt, goff, bbase, nbuk);
  part_fill_k<<<NBLK_P1, 256, 0, stream>>>(src, dst, goff, staging, E, nbuk);
  bucket_csr_k<<<nbuk, 256, 0, stream>>>(staging, bbase, csr_off, deg_inv, csr_src, N);

  const int gblocks = (N + 127) / 128;
  const int ablocks = (N + 15) / 16;
  // layer 1
  aggregate_k<<<ablocks, 256, 0, stream>>>(xb, csr_off, csr_src, deg_inv, agg, N);
  gemm_mfma_k<<<gblocks, 256, 0, stream>>>(agg, xb, Wt1, b1, hbuf, N);
  // layer 2
  aggregate_k<<<ablocks, 256, 0, stream>>>(hbuf, csr_off, csr_src, deg_inv, agg, N);
  gemm_mfma_k<<<gblocks, 256, 0, stream>>>(agg, hbuf, Wt2, b2, hbuf, N);
  // layer 3: yz = h@[W3l|W3r]+b (K=128), then fused mean-gather + log_softmax
  gemm3_mfma_k<<<gblocks, 256, 0, stream>>>(hbuf, Wt3b, bias3b, yz, N);
  agg_softmax_k<<<(N + 31) / 32, 256, 0, stream>>>(yz, csr_off, csr_src, deg_inv,
                                                   (float*)d_out, N);
}

// Round 11
// 389.405 us; speedup vs baseline: 1.2245x; 1.0510x over previous
//
#include <hip/hip_runtime.h>
#include <math.h>

#define D 128
#define NCLS 40
#define NBLK_P1 256      // partition blocks; bucket = 128 nodes, nbuk <= 1024

typedef unsigned int u32;
typedef __attribute__((ext_vector_type(8))) short short8;
typedef __attribute__((ext_vector_type(4))) float f32x4;

__device__ inline float bflo(u32 u){ return __uint_as_float(u << 16); }
__device__ inline float bfhi(u32 u){ return __uint_as_float(u & 0xffff0000u); }
__device__ inline u32 pack2bf(float a, float b){
  u32 ua = __float_as_uint(a), ub = __float_as_uint(b);
  ua += 0x7fffu + ((ua >> 16) & 1u);
  ub += 0x7fffu + ((ub >> 16) & 1u);
  return (ua >> 16) | (ub & 0xffff0000u);
}
__device__ inline unsigned short pack1bf(float a){
  u32 ua = __float_as_uint(a);
  ua += 0x7fffu + ((ua >> 16) & 1u);
  return (unsigned short)(ua >> 16);
}

// ---------------- fused prep: x->bf16 + weight converts + partition histogram ----------------
// block ranges: [0,nbX) f2bf | 128 Wt1/Wt2 | 32 Wt3b+bias3b | NBLK_P1 hist
__global__ __launch_bounds__(256) void prep_k(
    const float4* __restrict__ x4, uint2* __restrict__ xb, int n4,
    const float* __restrict__ W1l, const float* __restrict__ W1r, u32* __restrict__ Wt1,
    const float* __restrict__ W2l, const float* __restrict__ W2r, u32* __restrict__ Wt2,
    const float* __restrict__ W3l, const float* __restrict__ W3r,
    u32* __restrict__ Wt3b, float* __restrict__ bias3b, const float* __restrict__ b3,
    const int* __restrict__ dst, int* __restrict__ gcnt, int E, int nbuk, int nbX)
{
  __shared__ int cnt[1024];
  const int b = blockIdx.x;
  const int tid = threadIdx.x;
  if (b < nbX){
    int i = b * 256 + tid;
    if (i < n4){
      float4 v = x4[i];
      xb[i] = make_uint2(pack2bf(v.x, v.y), pack2bf(v.z, v.w));
    }
  } else if (b < nbX + 128){
    const bool first = (b < nbX + 64);
    const float* Wl = first ? W1l : W2l;
    const float* Wr = first ? W1r : W2r;
    u32* Wt = first ? Wt1 : Wt2;
    int i = ((b - nbX) & 63) * 256 + tid;         // 0..16383
    int nn = i >> 7, kp = i & 127;
    int k = kp * 2;
    float a, c;
    if (k < 128){ a = Wl[(size_t)k * 128 + nn]; c = Wl[(size_t)(k + 1) * 128 + nn]; }
    else        { a = Wr[(size_t)(k - 128) * 128 + nn]; c = Wr[(size_t)(k - 127) * 128 + nn]; }
    Wt[(size_t)nn * 128 + kp] = pack2bf(a, c);
  } else if (b < nbX + 160){
    // Wt3b[128 out][64 u32 k], K=128: out 0..39 = W3l^T, 64..103 = W3r^T, else 0
    int i = (b - nbX - 128) * 256 + tid;          // 0..8191
    if (i < 128 * 64){
      int nn = i >> 6, kp = i & 63;
      int k = kp * 2;
      float a = 0.f, c = 0.f;
      if (nn < NCLS){
        a = W3l[(size_t)k * NCLS + nn]; c = W3l[(size_t)(k + 1) * NCLS + nn];
      } else if (nn >= 64 && nn < 64 + NCLS){
        int cc = nn - 64;
        a = W3r[(size_t)k * NCLS + cc]; c = W3r[(size_t)(k + 1) * NCLS + cc];
      }
      Wt3b[(size_t)nn * 64 + kp] = pack2bf(a, c);
    }
    if (b == nbX + 128 && tid < 128)
      bias3b[tid] = (tid >= 64 && tid < 64 + NCLS) ? b3[tid - 64] : 0.f;
  } else {
    // partition histogram (LDS only)
    const int hb = b - nbX - 160;                 // 0..NBLK_P1-1
    for (int i = tid; i < nbuk; i += 256) cnt[i] = 0;
    __syncthreads();
    const int per = (E + NBLK_P1 - 1) / NBLK_P1;
    const int e0 = hb * per;
    const int e1 = min(e0 + per, E);
    for (int i = e0 + tid; i < e1; i += 256)
      atomicAdd(&cnt[dst[i] >> 7], 1);
    __syncthreads();
    for (int i = tid; i < nbuk; i += 256)
      gcnt[(size_t)hb * nbuk + i] = cnt[i];
  }
}

// ---------------- CSR build: chain-free LDS radix partition ----------------

// P1s: bucket totals -> exclusive bucket bases (bbase) + per-block offsets (goff)
__global__ __launch_bounds__(1024) void part_scan_k(
    const int* __restrict__ gcnt, int* __restrict__ goff,
    int* __restrict__ bbase, int nbuk)
{
  __shared__ int sm[1024];
  const int j = threadIdx.x;
  int btot = 0;
  if (j < nbuk)
    for (int i = 0; i < NBLK_P1; i++) btot += gcnt[(size_t)i * nbuk + j];
  sm[j] = btot;
  __syncthreads();
  int acc = btot;
  for (int off = 1; off < 1024; off <<= 1){
    int t = (j >= off) ? sm[j - off] : 0;
    __syncthreads();
    acc += t; sm[j] = acc;
    __syncthreads();
  }
  const int base = acc - btot;       // exclusive
  if (j < nbuk){
    bbase[j] = base;
    if (j == nbuk - 1) bbase[nbuk] = base + btot;   // == E
    int run = base;
    for (int i = 0; i < NBLK_P1; i++){
      goff[(size_t)i * nbuk + j] = run;
      run += gcnt[(size_t)i * nbuk + j];
    }
  }
}

// P1b: scatter edges into bucket staging; entry = (src<<7)|dst_local (4B; needs src < 2^25)
__global__ __launch_bounds__(256) void part_fill_k(
    const int* __restrict__ src, const int* __restrict__ dst,
    const int* __restrict__ goff, u32* __restrict__ staging,
    int E, int nbuk)
{
  __shared__ int boff[1024];
  __shared__ int cur[1024];
  const int tid = threadIdx.x;
  for (int i = tid; i < nbuk; i += 256){
    boff[i] = goff[(size_t)blockIdx.x * nbuk + i];
    cur[i] = 0;
  }
  __syncthreads();
  const int per = (E + NBLK_P1 - 1) / NBLK_P1;
  const int e0 = blockIdx.x * per;
  const int e1 = min(e0 + per, E);
  for (int i = e0 + tid; i < e1; i += 256){
    int d = dst[i];
    int s = src[i];
    int b = d >> 7;
    int p = atomicAdd(&cur[b], 1);
    staging[boff[b] + p] = ((u32)s << 7) | (u32)(d & 127);
  }
}

// P2: one block per bucket. LDS degree histogram -> local scan -> csr_off/deg_inv,
// then ordered csr_src scatter confined to the bucket's ~contiguous window.
__global__ __launch_bounds__(256) void bucket_csr_k(
    const u32* __restrict__ staging, const int* __restrict__ bbase,
    int* __restrict__ csr_off, float* __restrict__ deg_inv,
    int* __restrict__ csr_src, int N)
{
  __shared__ int ldeg[128];
  __shared__ int sm[128];
  __shared__ int lbase[128];
  __shared__ int lpos[128];
  const int b = blockIdx.x;
  const int node0 = b << 7;
  const int tid = threadIdx.x;
  if (tid < 128) ldeg[tid] = 0;
  __syncthreads();
  const int lo = bbase[b], hi = bbase[b + 1];
  for (int i = lo + tid; i < hi; i += 256)
    atomicAdd(&ldeg[staging[i] & 127u], 1);
  __syncthreads();
  if (tid < 128) sm[tid] = ldeg[tid];
  __syncthreads();
  for (int off = 1; off < 128; off <<= 1){
    int t = (tid >= off && tid < 128) ? sm[tid - off] : 0;
    __syncthreads();
    if (tid < 128) sm[tid] += t;
    __syncthreads();
  }
  if (tid < 128){
    const int excl = sm[tid] - ldeg[tid];
    lbase[tid] = lo + excl;
    lpos[tid] = 0;
    const int node = node0 + tid;
    if (node < N){
      csr_off[node] = lo + excl;
      deg_inv[node] = 1.0f / fmaxf((float)ldeg[tid], 1.0f);
    } else if (node == N){
      csr_off[N] = lo + excl;
    }
  }
  if (tid == 0 && b == (int)gridDim.x - 1) csr_off[N] = hi;   // covers N%128==0
  __syncthreads();
  for (int i = lo + tid; i < hi; i += 256){
    u32 v = staging[i];
    int dloc = (int)(v & 127u);
    int p = atomicAdd(&lpos[dloc], 1);
    csr_src[lbase[dloc] + p] = (int)(v >> 7);
  }
}

// ---------------- mean aggregation (bf16 gather via CSR), 8-way unrolled ----------------
__device__ inline void add8(float* acc, uint4 v){
  acc[0] += bflo(v.x); acc[1] += bfhi(v.x);
  acc[2] += bflo(v.y); acc[3] += bfhi(v.y);
  acc[4] += bflo(v.z); acc[5] += bfhi(v.z);
  acc[6] += bflo(v.w); acc[7] += bfhi(v.w);
}

__global__ __launch_bounds__(256) void aggregate_k(
    const u32* __restrict__ feat, const int* __restrict__ coff,
    const int* __restrict__ csr_src, const float* __restrict__ deg_inv,
    u32* __restrict__ agg, int n)
{
  const int g = threadIdx.x >> 4;
  const int lane = threadIdx.x & 15;
  const int node = blockIdx.x * 16 + g;
  if (node >= n) return;
  const int lo = coff[node], hi = coff[node + 1];
  const uint4* __restrict__ f4 = (const uint4*)feat;
  float acc[8] = {0.f,0.f,0.f,0.f,0.f,0.f,0.f,0.f};
  int e = lo;
  for (; e + 7 < hi; e += 8){
    int s0 = csr_src[e],     s1 = csr_src[e + 1];
    int s2 = csr_src[e + 2], s3 = csr_src[e + 3];
    int s4 = csr_src[e + 4], s5 = csr_src[e + 5];
    int s6 = csr_src[e + 6], s7 = csr_src[e + 7];
    uint4 v0 = f4[(size_t)s0 * 16 + lane];
    uint4 v1 = f4[(size_t)s1 * 16 + lane];
    uint4 v2 = f4[(size_t)s2 * 16 + lane];
    uint4 v3 = f4[(size_t)s3 * 16 + lane];
    uint4 v4 = f4[(size_t)s4 * 16 + lane];
    uint4 v5 = f4[(size_t)s5 * 16 + lane];
    uint4 v6 = f4[(size_t)s6 * 16 + lane];
    uint4 v7 = f4[(size_t)s7 * 16 + lane];
    add8(acc, v0); add8(acc, v1); add8(acc, v2); add8(acc, v3);
    add8(acc, v4); add8(acc, v5); add8(acc, v6); add8(acc, v7);
  }
  for (; e + 3 < hi; e += 4){
    int s0 = csr_src[e],     s1 = csr_src[e + 1];
    int s2 = csr_src[e + 2], s3 = csr_src[e + 3];
    uint4 v0 = f4[(size_t)s0 * 16 + lane];
    uint4 v1 = f4[(size_t)s1 * 16 + lane];
    uint4 v2 = f4[(size_t)s2 * 16 + lane];
    uint4 v3 = f4[(size_t)s3 * 16 + lane];
    add8(acc, v0); add8(acc, v1); add8(acc, v2); add8(acc, v3);
  }
  for (; e < hi; ++e){
    uint4 v0 = f4[(size_t)csr_src[e] * 16 + lane];
    add8(acc, v0);
  }
  const float di = deg_inv[node];
  uint4 o;
  o.x = pack2bf(acc[0] * di, acc[1] * di);
  o.y = pack2bf(acc[2] * di, acc[3] * di);
  o.z = pack2bf(acc[4] * di, acc[5] * di);
  o.w = pack2bf(acc[6] * di, acc[7] * di);
  ((uint4*)agg)[(size_t)node * 16 + lane] = o;
}

// ---------------- MFMA dense: out = relu([A1|A2] @ Wt^T + bias), bf16, K=256 ----------------
__global__ __launch_bounds__(256) void gemm_mfma_k(
    const u32* __restrict__ A1, const u32* __restrict__ A2,
    const u32* __restrict__ Wt, const float* __restrict__ bias,
    u32* __restrict__ out, int n)
{
  __shared__ u32 As_u[128 * 20];   // row stride 20 u32 = 40 bf16
  __shared__ u32 Bs_u[128 * 20];
  const int tid = threadIdx.x;
  const int row0 = blockIdx.x * 128;
  const int l = tid & 63, w = tid >> 6;
  const int lm = l & 15, lq = l >> 4;

  f32x4 acc[2][8];
  #pragma unroll
  for (int mi = 0; mi < 2; mi++)
    #pragma unroll
    for (int ni = 0; ni < 8; ni++) acc[mi][ni] = (f32x4){0.f, 0.f, 0.f, 0.f};

  for (int kt = 0; kt < 8; ++kt){
    const u32* Ap = (kt < 4) ? A1 : A2;
    const int ko = (kt & 3) * 16;
    #pragma unroll
    for (int i = 0; i < 2; i++){
      int chunk = tid + 256 * i;
      int row = chunk >> 2, q = chunk & 3;
      uint4 av = make_uint4(0, 0, 0, 0);
      int gr = row0 + row;
      if (gr < n) av = *(const uint4*)(Ap + (size_t)gr * 64 + ko + q * 4);
      *(uint4*)&As_u[row * 20 + q * 4] = av;
      uint4 bv = *(const uint4*)(Wt + (size_t)row * 128 + kt * 16 + q * 4);
      *(uint4*)&Bs_u[row * 20 + q * 4] = bv;
    }
    __syncthreads();
    short8 af0 = *(const short8*)&As_u[(w * 32 + lm) * 20 + lq * 4];
    short8 af1 = *(const short8*)&As_u[(w * 32 + 16 + lm) * 20 + lq * 4];
    #pragma unroll
    for (int ni = 0; ni < 8; ni++){
      short8 bf = *(const short8*)&Bs_u[(ni * 16 + lm) * 20 + lq * 4];
      acc[0][ni] = __builtin_amdgcn_mfma_f32_16x16x32_bf16(af0, bf, acc[0][ni], 0, 0, 0);
      acc[1][ni] = __builtin_amdgcn_mfma_f32_16x16x32_bf16(af1, bf, acc[1][ni], 0, 0, 0);
    }
    __syncthreads();
  }

  float bb[8];
  #pragma unroll
  for (int ni = 0; ni < 8; ni++) bb[ni] = bias[ni * 16 + lm];
  unsigned short* outp = (unsigned short*)out;
  #pragma unroll
  for (int mi = 0; mi < 2; mi++){
    #pragma unroll
    for (int r = 0; r < 4; r++){
      int row = row0 + w * 32 + mi * 16 + lq * 4 + r;
      if (row < n){
        #pragma unroll
        for (int ni = 0; ni < 8; ni++){
          float v = fmaxf(acc[mi][ni][r] + bb[ni], 0.f);
          outp[(size_t)row * 128 + ni * 16 + lm] = pack1bf(v);
        }
      }
    }
  }
}

// ---------------- layer-3 pre-GEMM (K=128, no relu): yz = h @ Wt3b^T + bias3b ----------------
__global__ __launch_bounds__(256) void gemm3_mfma_k(
    const u32* __restrict__ A, const u32* __restrict__ Wt3b,
    const float* __restrict__ bias, u32* __restrict__ out, int n)
{
  __shared__ u32 As_u[128 * 20];
  __shared__ u32 Bs_u[128 * 20];
  const int tid = threadIdx.x;
  const int row0 = blockIdx.x * 128;
  const int l = tid & 63, w = tid >> 6;
  const int lm = l & 15, lq = l >> 4;

  f32x4 acc[2][8];
  #pragma unroll
  for (int mi = 0; mi < 2; mi++)
    #pragma unroll
    for (int ni = 0; ni < 8; ni++) acc[mi][ni] = (f32x4){0.f, 0.f, 0.f, 0.f};

  for (int kt = 0; kt < 4; ++kt){
    #pragma unroll
    for (int i = 0; i < 2; i++){
      int chunk = tid + 256 * i;
      int row = chunk >> 2, q = chunk & 3;
      uint4 av = make_uint4(0, 0, 0, 0);
      int gr = row0 + row;
      if (gr < n) av = *(const uint4*)(A + (size_t)gr * 64 + kt * 16 + q * 4);
      *(uint4*)&As_u[row * 20 + q * 4] = av;
      uint4 bv = *(const uint4*)(Wt3b + (size_t)row * 64 + kt * 16 + q * 4);
      *(uint4*)&Bs_u[row * 20 + q * 4] = bv;
    }
    __syncthreads();
    short8 af0 = *(const short8*)&As_u[(w * 32 + lm) * 20 + lq * 4];
    short8 af1 = *(const short8*)&As_u[(w * 32 + 16 + lm) * 20 + lq * 4];
    #pragma unroll
    for (int ni = 0; ni < 8; ni++){
      short8 bf = *(const short8*)&Bs_u[(ni * 16 + lm) * 20 + lq * 4];
      acc[0][ni] = __builtin_amdgcn_mfma_f32_16x16x32_bf16(af0, bf, acc[0][ni], 0, 0, 0);
      acc[1][ni] = __builtin_amdgcn_mfma_f32_16x16x32_bf16(af1, bf, acc[1][ni], 0, 0, 0);
    }
    __syncthreads();
  }

  float bb[8];
  #pragma unroll
  for (int ni = 0; ni < 8; ni++) bb[ni] = bias[ni * 16 + lm];
  unsigned short* outp = (unsigned short*)out;
  #pragma unroll
  for (int mi = 0; mi < 2; mi++){
    #pragma unroll
    for (int r = 0; r < 4; r++){
      int row = row0 + w * 32 + mi * 16 + lq * 4 + r;
      if (row < n){
        #pragma unroll
        for (int ni = 0; ni < 8; ni++){
          float v = acc[mi][ni][r] + bb[ni];
          outp[(size_t)row * 128 + ni * 16 + lm] = pack1bf(v);
        }
      }
    }
  }
}

// ---------------- fused: out = log_softmax(mean-gather(y) + z), 8-way unrolled ----------------
__global__ __launch_bounds__(256) void agg_softmax_k(
    const u32* __restrict__ yz, const int* __restrict__ coff,
    const int* __restrict__ csr_src, const float* __restrict__ deg_inv,
    float* __restrict__ out, int n)
{
  const int g = threadIdx.x >> 3;
  const int lane = threadIdx.x & 7;
  const int node = blockIdx.x * 32 + g;
  if (node >= n) return;
  const int lo = coff[node], hi = coff[node + 1];
  const uint4* __restrict__ f4 = (const uint4*)yz;    // 16 uint4 per row; y = first 8
  float acc[8] = {0.f,0.f,0.f,0.f,0.f,0.f,0.f,0.f};
  int e = lo;
  for (; e + 7 < hi; e += 8){
    int s0 = csr_src[e],     s1 = csr_src[e + 1];
    int s2 = csr_src[e + 2], s3 = csr_src[e + 3];
    int s4 = csr_src[e + 4], s5 = csr_src[e + 5];
    int s6 = csr_src[e + 6], s7 = csr_src[e + 7];
    uint4 v0 = f4[(size_t)s0 * 16 + lane];
    uint4 v1 = f4[(size_t)s1 * 16 + lane];
    uint4 v2 = f4[(size_t)s2 * 16 + lane];
    uint4 v3 = f4[(size_t)s3 * 16 + lane];
    uint4 v4 = f4[(size_t)s4 * 16 + lane];
    uint4 v5 = f4[(size_t)s5 * 16 + lane];
    uint4 v6 = f4[(size_t)s6 * 16 + lane];
    uint4 v7 = f4[(size_t)s7 * 16 + lane];
    add8(acc, v0); add8(acc, v1); add8(acc, v2); add8(acc, v3);
    add8(acc, v4); add8(acc, v5); add8(acc, v6); add8(acc, v7);
  }
  for (; e + 3 < hi; e += 4){
    int s0 = csr_src[e],     s1 = csr_src[e + 1];
    int s2 = csr_src[e + 2], s3 = csr_src[e + 3];
    uint4 v0 = f4[(size_t)s0 * 16 + lane];
    uint4 v1 = f4[(size_t)s1 * 16 + lane];
    uint4 v2 = f4[(size_t)s2 * 16 + lane];
    uint4 v3 = f4[(size_t)s3 * 16 + lane];
    add8(acc, v0); add8(acc, v1); add8(acc, v2); add8(acc, v3);
  }
  for (; e < hi; ++e){
    uint4 v0 = f4[(size_t)csr_src[e] * 16 + lane];
    add8(acc, v0);
  }
  const float di = deg_inv[node];
  uint4 zv = f4[(size_t)node * 16 + 8 + lane];
  float v[8];
  v[0] = acc[0] * di + bflo(zv.x); v[1] = acc[1] * di + bfhi(zv.x);
  v[2] = acc[2] * di + bflo(zv.y); v[3] = acc[3] * di + bfhi(zv.y);
  v[4] = acc[4] * di + bflo(zv.z); v[5] = acc[5] * di + bfhi(zv.z);
  v[6] = acc[6] * di + bflo(zv.w); v[7] = acc[7] * di + bfhi(zv.w);
  const bool valid = (lane < 5);
  float m = -INFINITY;
  if (valid){
    #pragma unroll
    for (int j = 0; j < 8; j++) m = fmaxf(m, v[j]);
  }
  #pragma unroll
  for (int off = 1; off < 8; off <<= 1) m = fmaxf(m, __shfl_xor(m, off, 64));
  float s = 0.f;
  if (valid){
    #pragma unroll
    for (int j = 0; j < 8; j++) s += __expf(v[j] - m);
  }
  #pragma unroll
  for (int off = 1; off < 8; off <<= 1) s += __shfl_xor(s, off, 64);
  const float ls = m + logf(s);
  if (valid){
    float* op = out + (size_t)node * NCLS + lane * 8;
    *(float4*)op     = make_float4(v[0]-ls, v[1]-ls, v[2]-ls, v[3]-ls);
    *(float4*)(op+4) = make_float4(v[4]-ls, v[5]-ls, v[6]-ls, v[7]-ls);
  }
}

// ---------------- launch ----------------

extern "C" void kernel_launch(void* const* d_in, const int* in_sizes, int n_in,
                              void* d_out, int out_size, void* d_ws, size_t ws_size,
                              hipStream_t stream) {
  const float* x   = (const float*)d_in[0];
  const int*   ei  = (const int*)d_in[1];
  const float* W1l = (const float*)d_in[2];
  const float* b1  = (const float*)d_in[3];
  const float* W1r = (const float*)d_in[4];
  const float* W2l = (const float*)d_in[5];
  const float* b2  = (const float*)d_in[6];
  const float* W2r = (const float*)d_in[7];
  const float* W3l = (const float*)d_in[8];
  const float* b3  = (const float*)d_in[9];
  const float* W3r = (const float*)d_in[10];

  const int N = in_sizes[0] / D;       // 100000
  const int E = in_sizes[1] / 2;       // 1600000
  const int* src = ei;
  const int* dst = ei + E;
  const int nbuk = (N + 127) >> 7;     // 782 buckets of 128 nodes

  char* ws = (char*)d_ws;
  auto alloc = [&](size_t bytes) -> void* {
    void* p = (void*)ws;
    ws += (bytes + 255) & ~(size_t)255;
    return p;
  };
  int*   csr_off  = (int*)  alloc((size_t)(N + 1) * 4);
  float* deg_inv  = (float*)alloc((size_t)N * 4);
  int*   csr_src  = (int*)  alloc((size_t)E * 4);
  u32*   staging  = (u32*)  alloc((size_t)E * 4);
  int*   gcnt     = (int*)  alloc((size_t)NBLK_P1 * nbuk * 4);
  int*   goff     = (int*)  alloc((size_t)NBLK_P1 * nbuk * 4);
  int*   bbase    = (int*)  alloc((size_t)(nbuk + 1) * 4);
  u32*   xb       = (u32*)  alloc((size_t)N * D * 2);
  u32*   agg      = (u32*)  alloc((size_t)N * D * 2);
  u32*   hbuf     = (u32*)  alloc((size_t)N * D * 2);
  u32*   yz       = (u32*)  alloc((size_t)N * D * 2);
  u32*   Wt1      = (u32*)  alloc((size_t)128 * 128 * 4);
  u32*   Wt2      = (u32*)  alloc((size_t)128 * 128 * 4);
  u32*   Wt3b    = (u32*)  alloc((size_t)128 * 64 * 4);
  float* bias3b   = (float*)alloc((size_t)128 * 4);

  // fused prep: x->bf16, weight converts, partition histogram
  const int n4 = N * D / 4;
  const int nbX = (n4 + 255) / 256;
  prep_k<<<nbX + 160 + NBLK_P1, 256, 0, stream>>>(
      (const float4*)x, (uint2*)xb, n4,
      W1l, W1r, Wt1, W2l, W2r, Wt2,
      W3l, W3r, Wt3b, bias3b, b3,
      dst, gcnt, E, nbuk, nbX);

  // CSR build: bucket scan -> partition -> per-bucket deg+scan+fill
  part_scan_k<<<1, 1024, 0, stream>>>(gcnt, goff, bbase, nbuk);
  part_fill_k<<<NBLK_P1, 256, 0, stream>>>(src, dst, goff, staging, E, nbuk);
  bucket_csr_k<<<nbuk, 256, 0, stream>>>(staging, bbase, csr_off, deg_inv, csr_src, N);

  const int gblocks = (N + 127) / 128;
  const int ablocks = (N + 15) / 16;
  // layer 1
  aggregate_k<<<ablocks, 256, 0, stream>>>(xb, csr_off, csr_src, deg_inv, agg, N);
  gemm_mfma_k<<<gblocks, 256, 0, stream>>>(agg, xb, Wt1, b1, hbuf, N);
  // layer 2
  aggregate_k<<<ablocks, 256, 0, stream>>>(hbuf, csr_off, csr_src, deg_inv, agg, N);
  gemm_mfma_k<<<gblocks, 256, 0, stream>>>(agg, hbuf, Wt2, b2, hbuf, N);
  // layer 3: yz = h@[W3l|W3r]+b (K=128), then fused mean-gather + log_softmax
  gemm3_mfma_k<<<gblocks, 256, 0, stream>>>(hbuf, Wt3b, bias3b, yz, N);
  agg_softmax_k<<<(N + 31) / 32, 256, 0, stream>>>(yz, csr_off, csr_src, deg_inv,
                                                   (float*)d_out, N);
}